// Round 6
// baseline (19675.914 us; speedup 1.0000x reference)
//
#include <hip/hip_runtime.h>
#include <stdint.h>
#include <stddef.h>

typedef __bf16 bf16x8 __attribute__((ext_vector_type(8)));
typedef float f32x4 __attribute__((ext_vector_type(4)));
typedef uint32_t u32x4v __attribute__((ext_vector_type(4)));

#define MFMA16(a, b, c) __builtin_amdgcn_mfma_f32_16x16x32_bf16((a), (b), (c), 0, 0, 0)

// problem dims
#define TSTEPS 1024
#define NDIM   64
#define NKC    10     // gate K-chunks: 0,1 = noise(64); 2..9 = h chunks of 32
#define NGT    64
#define MB     16
#define GROUPS 32
#define SLICES 8

// workspace layout (bytes)
#define GOFF    ((size_t)0)
#define GBYTES  ((size_t)NGT * NKC * 1024)       // 655360
#define W1OFF   (GOFF + GBYTES)
#define W1BYTES ((size_t)16 * 8 * 1024)          // 131072
#define BOFF    (W1OFF + W1BYTES)                // 1024 f32 reordered gate bias
#define XOFF    (BOFF + 4096)                    // ids (1KB) + payF (1MB) + payS (1MB)
#define IDSB    ((size_t)1024)
#define PAYB    ((size_t)256 * 2 * 512 * 4)      // 1 MiB per flavor
#define WSNEED  (XOFF + IDSB + 2 * PAYB)

__device__ __forceinline__ uint16_t f2bf(float f) {
    union { float f; uint32_t u; } v; v.f = f;
    return (uint16_t)((v.u + 0x7FFFu + ((v.u >> 16) & 1u)) >> 16);  // RNE
}
__device__ __forceinline__ float fsig(float x) { return 1.0f / (1.0f + __expf(-x)); }
__device__ __forceinline__ float ftanh(float x) { return 2.0f / (1.0f + __expf(-2.0f * x)) - 1.0f; }

__device__ __forceinline__ void bar_lgkm() {
    asm volatile("s_waitcnt lgkmcnt(0)" ::: "memory");
    __builtin_amdgcn_s_barrier();
    asm volatile("" ::: "memory");
}

__device__ __forceinline__ bool tagpair_ok(u32x4v A, u32x4v B, uint32_t tg) {
    return ((A[0] >> 16) == tg) & ((A[1] >> 16) == tg) & ((A[2] >> 16) == tg) & ((A[3] >> 16) == tg)
         & ((B[0] >> 16) == tg) & ((B[1] >> 16) == tg) & ((B[2] >> 16) == tg) & ((B[3] >> 16) == tg);
}
__device__ __forceinline__ bf16x8 repack(u32x4v A, u32x4v B) {
    uint4 r;
    r.x = (A[0] & 0xffffu) | (A[1] << 16);
    r.y = (A[2] & 0xffffu) | (A[3] << 16);
    r.z = (B[0] & 0xffffu) | (B[1] << 16);
    r.w = (B[2] & 0xffffu) | (B[3] << 16);
    return __builtin_bit_cast(bf16x8, r);
}
__device__ __forceinline__ void spoll2(const uint32_t* p, u32x4v& A, u32x4v& B) {
    A[0] = __hip_atomic_load(p + 0, __ATOMIC_RELAXED, __HIP_MEMORY_SCOPE_AGENT);
    A[1] = __hip_atomic_load(p + 1, __ATOMIC_RELAXED, __HIP_MEMORY_SCOPE_AGENT);
    A[2] = __hip_atomic_load(p + 2, __ATOMIC_RELAXED, __HIP_MEMORY_SCOPE_AGENT);
    A[3] = __hip_atomic_load(p + 3, __ATOMIC_RELAXED, __HIP_MEMORY_SCOPE_AGENT);
    B[0] = __hip_atomic_load(p + 4, __ATOMIC_RELAXED, __HIP_MEMORY_SCOPE_AGENT);
    B[1] = __hip_atomic_load(p + 5, __ATOMIC_RELAXED, __HIP_MEMORY_SCOPE_AGENT);
    B[2] = __hip_atomic_load(p + 6, __ATOMIC_RELAXED, __HIP_MEMORY_SCOPE_AGENT);
    B[3] = __hip_atomic_load(p + 7, __ATOMIC_RELAXED, __HIP_MEMORY_SCOPE_AGENT);
}

// 8 L2-coherent (sc0) dwordx4 loads + single drain.
// NOTE gfx950 syntax: offset immediate BEFORE cache modifier ("offset:16 sc0").
#define FPOLL(A0, A1, A2, A3, Q0, Q1, Q2, Q3, Q4, Q5, Q6, Q7)                 \
    asm volatile(                                                             \
        "global_load_dwordx4 %0, %8, off sc0\n\t"                             \
        "global_load_dwordx4 %1, %8, off offset:16 sc0\n\t"                   \
        "global_load_dwordx4 %2, %9, off sc0\n\t"                             \
        "global_load_dwordx4 %3, %9, off offset:16 sc0\n\t"                   \
        "global_load_dwordx4 %4, %10, off sc0\n\t"                            \
        "global_load_dwordx4 %5, %10, off offset:16 sc0\n\t"                  \
        "global_load_dwordx4 %6, %11, off sc0\n\t"                            \
        "global_load_dwordx4 %7, %11, off offset:16 sc0\n\t"                  \
        "s_waitcnt vmcnt(0)"                                                  \
        : "=&v"(Q0), "=&v"(Q1), "=&v"(Q2), "=&v"(Q3),                         \
          "=&v"(Q4), "=&v"(Q5), "=&v"(Q6), "=&v"(Q7)                          \
        : "v"(A0), "v"(A1), "v"(A2), "v"(A3)                                  \
        : "memory")

#define PROC(P, QA, QB) {                                                     \
    bf16x8 bv_ = repack(QA, QB);                                              \
    gacc = MFMA16(__builtin_bit_cast(bf16x8, gw[2 + (P)]), bv_, gacc);        \
    h0   = MFMA16(__builtin_bit_cast(bf16x8, w1w[(P)]),     bv_, h0);         \
    h1   = MFMA16(__builtin_bit_cast(bf16x8, w1w[8 + (P)]), bv_, h1); }

#define HALF(PA, PB, PC, PD) {                                                \
    u32x4v q0, q1, q2, q3, q4, q5, q6, q7;                                    \
    bool done_ = false;                                                       \
    if (fm) {                                                                 \
        int spins_ = 0;                                                       \
        for (;;) {                                                            \
            FPOLL(AF[PA] + paro, AF[PB] + paro, AF[PC] + paro, AF[PD] + paro, \
                  q0, q1, q2, q3, q4, q5, q6, q7);                            \
            bool ok_ = tagpair_ok(q0, q1, tg) & tagpair_ok(q2, q3, tg) &      \
                       tagpair_ok(q4, q5, tg) & tagpair_ok(q6, q7, tg);       \
            if (__all(ok_)) { done_ = true; break; }                          \
            if (++spins_ > 6000) { fm = false; break; }                       \
        }                                                                     \
    }                                                                         \
    if (!done_) {                                                             \
        for (;;) {                                                            \
            spoll2(payS + ASW[PA] + parw, q0, q1);                            \
            spoll2(payS + ASW[PB] + parw, q2, q3);                            \
            spoll2(payS + ASW[PC] + parw, q4, q5);                            \
            spoll2(payS + ASW[PD] + parw, q6, q7);                            \
            bool ok_ = tagpair_ok(q0, q1, tg) & tagpair_ok(q2, q3, tg) &      \
                       tagpair_ok(q4, q5, tg) & tagpair_ok(q6, q7, tg);       \
            if (__all(ok_)) break;                                            \
        }                                                                     \
    }                                                                         \
    PROC(PA, q0, q1); PROC(PB, q2, q3); PROC(PC, q4, q5); PROC(PD, q6, q7); }

// ---- prep: gate weights [1024 x 320] bf16, frag-major
__global__ void prep_gates(const float* __restrict__ W_ih, const float* __restrict__ W_hh,
                           char* __restrict__ ws) {
    int F = blockIdx.x;
    int T = F / NKC, kc = F - T * NKC;
    int l = threadIdx.x;
    int row  = 16 * T + (l & 15);
    int unit = row >> 2, gt = row & 3;
    int orig = gt * 256 + unit;
    uint32_t w[4];
#pragma unroll
    for (int p = 0; p < 4; ++p) {
        float v[2];
#pragma unroll
        for (int e = 0; e < 2; ++e) {
            int k = 32 * kc + 8 * (l >> 4) + 2 * p + e;
            v[e] = (k < 64) ? W_ih[orig * 67 + 3 + k] : W_hh[orig * 256 + (k - 64)];
        }
        w[p] = (uint32_t)f2bf(v[0]) | ((uint32_t)f2bf(v[1]) << 16);
    }
    *(uint4*)(ws + GOFF + (size_t)F * 1024 + (size_t)l * 16) = make_uint4(w[0], w[1], w[2], w[3]);
}

__global__ void prep_w1(const float* __restrict__ W1, char* __restrict__ ws) {
    int F = blockIdx.x;
    int T = F / 8, kc = F - T * 8;
    int l = threadIdx.x;
    int row = 16 * T + (l & 15);
    uint32_t w[4];
#pragma unroll
    for (int p = 0; p < 4; ++p) {
        int k = 32 * kc + 8 * (l >> 4) + 2 * p;
        w[p] = (uint32_t)f2bf(W1[row * 256 + k]) | ((uint32_t)f2bf(W1[row * 256 + k + 1]) << 16);
    }
    *(uint4*)(ws + W1OFF + (size_t)F * 1024 + (size_t)l * 16) = make_uint4(w[0], w[1], w[2], w[3]);
}

__global__ void prep_small(const float* __restrict__ b_ih, const float* __restrict__ b_hh,
                           char* __restrict__ ws) {
    int t = threadIdx.x;
    float* sb = (float*)(ws + BOFF);
    if (t < 1024) {
        int unit = t >> 2, gt = t & 3;
        int orig = gt * 256 + unit;
        sb[t] = b_ih[orig] + b_hh[orig];
    }
}

// ---- main: 256 blocks (32 groups x 8 slices, XCD-colocated), h exchange via L2 mailbox
__global__ __launch_bounds__(512, 2) void lstm_main(
        const float* __restrict__ noise, const float* __restrict__ gap,
        const float* __restrict__ W_ih, const float* __restrict__ b1p,
        const float* __restrict__ W2p, const float* __restrict__ b2p,
        char* __restrict__ ws, float* __restrict__ out) {
    __shared__ uint16_t actn[2][16][64];   // noise tile, parity dbuf, XOR-swizzled
    __shared__ float dp_part[2][16][9];
    __shared__ float gxy[2][16][2];
    __shared__ int s_gf;

    const int tid  = threadIdx.x;
    const int w    = tid >> 6;
    const int lane = tid & 63;
    const int q    = lane >> 4;
    const int col  = lane & 15;
    // XCD-colocating swizzle: n%8 -> XCD (round-robin assumption, runtime-verified)
    const int n    = blockIdx.x;
    const int x_   = n & 7, k_ = n >> 3;
    const int g    = x_ * 4 + (k_ & 3);
    const int s    = k_ >> 2;
    const int b0   = g * MB;
    const int swz  = (col & 7) << 3;
    const int myidx = g * 8 + s;

    const uint4* gfr  = (const uint4*)(ws + GOFF);
    const uint4* w1fr = (const uint4*)(ws + W1OFF);
    const float* bias = (const float*)(ws + BOFF);
    uint32_t* ids  = (uint32_t*)(ws + XOFF);
    char*     payF = ws + XOFF + IDSB;
    uint32_t* payS = (uint32_t*)(ws + XOFF + IDSB + PAYB);

    // ---- weights -> VGPRs
    const int T = 8 * s + w;
    uint4 gw[NKC];
#pragma unroll
    for (int kc = 0; kc < NKC; ++kc) gw[kc] = gfr[(size_t)(T * NKC + kc) * 64 + lane];
    uint4 w1w[16];
#pragma unroll
    for (int i = 0; i < 2; ++i)
#pragma unroll
        for (int kc = 0; kc < 8; ++kc)
            w1w[i * 8 + kc] = w1fr[(size_t)((2 * w + i) * 8 + kc) * 64 + lane];

    const int rb = 16 * T + 4 * q;
    const float bI = bias[rb], bF = bias[rb + 1], bG = bias[rb + 2], bO = bias[rb + 3];
    float wx0[4], wx1[4], wx2[4];
#pragma unroll
    for (int r = 0; r < 4; ++r) {
        int row = rb + r;
        int orig = (row & 3) * 256 + (row >> 2);
        wx0[r] = W_ih[orig * 67 + 0];
        wx1[r] = W_ih[orig * 67 + 1];
        wx2[r] = W_ih[orig * 67 + 2] * 24.0f;
    }
    float b1r[8], w2r[8];
#pragma unroll
    for (int a = 0; a < 2; ++a)
#pragma unroll
        for (int r = 0; r < 4; ++r) {
            int row = 32 * w + 16 * a + 4 * q + r;
            b1r[4 * a + r] = b1p[row];
            w2r[4 * a + r] = W2p[row];
        }
    const float b2v = b2p[0];

    // ---- XCC-id exchange -> groupfast (known-good agent path, one-time)
    uint32_t myx;
    asm volatile("s_getreg_b32 %0, hwreg(HW_REG_XCC_ID)" : "=s"(myx));
    if (tid == 0)
        __hip_atomic_store(&ids[myidx], 0x100u | (myx & 0xffu),
                           __ATOMIC_RELAXED, __HIP_MEMORY_SCOPE_AGENT);
    if (tid < 8) {
        uint32_t v;
        do { v = __hip_atomic_load(&ids[g * 8 + tid], __ATOMIC_RELAXED,
                                   __HIP_MEMORY_SCOPE_AGENT); } while (!(v & 0x100u));
        unsigned long long bal = __ballot((v & 0xffu) == (myx & 0xffu));
        if (tid == 0) s_gf = ((bal & 0xffull) == 0xffull) ? 1 : 0;
    }

    // ---- mailbox addresses (entry order = peer index p; self included)
    uint64_t AF[8]; int ASW[8];
#pragma unroll
    for (int p = 0; p < 8; ++p) {
        AF[p]  = (uint64_t)(uintptr_t)(payF + (size_t)(g * 8 + p) * 4096
                                       + (size_t)(512 * q + 32 * col));
        ASW[p] = (g * 8 + p) * 1024 + 128 * q + 8 * col;
    }
    const int U = 4 * w + q;                                   // own unit within slice
    const int widx = 128 * (U >> 3) + 8 * col + (U & 7);       // own mailbox word
    const uint64_t WFa = (uint64_t)(uintptr_t)(payF + (size_t)myidx * 4096 + 4 * widx);
    const int WSw = myidx * 1024 + widx;

    // ---- prefetch t=0
    const int nbr = tid >> 5, nj = (tid & 31) * 2;
    const int nsw = (nbr & 7) << 3;
    const float* nptr = noise + (size_t)(b0 + nbr) * TSTEPS * NDIM + nj;
    float2 npf = *(const float2*)nptr;
    const bool xlead = (w == 7 && lane < 16);
    float2 gpf = make_float2(0.f, 0.f);
    if (xlead) gpf = *(const float2*)(gap + (size_t)(b0 + col) * (TSTEPS + 1) * 2);

    float creg = 0.f;
    const f32x4 fz = {0.f, 0.f, 0.f, 0.f};

    __syncthreads();
    bool fm = (s_gf != 0);

#pragma unroll 1
    for (int t = 0; t <= TSTEPS; ++t) {
        const int par = t & 1;
        const uint32_t tg = (uint32_t)t;
        const uint64_t paro = par ? 2048u : 0u;
        const int parw = par << 9;

        // ---- pre-barrier: stage noise(t); xlead stages gap + writes out cols 0,1
        if (t < TSTEPS) {
            uint32_t nv = (uint32_t)f2bf(npf.x) | ((uint32_t)f2bf(npf.y) << 16);
            *(uint32_t*)&actn[par][nbr][nj ^ nsw] = nv;
        }
        if (xlead) {
            gxy[par][col][0] = gpf.x; gxy[par][col][1] = gpf.y;
            if (s == 0) {
                float* o = out + ((size_t)(b0 + col) * (TSTEPS + 1) + t) * 3;
                o[0] = gpf.x; o[1] = gpf.y;
            }
            if (t < TSTEPS)
                gpf = *(const float2*)(gap + ((size_t)(b0 + col) * (TSTEPS + 1) + (t + 1)) * 2);
        }

        // ---- poll 8 slices (incl. self) + h-MFMAs, straight from registers
        f32x4 h0 = fz, h1 = fz, gacc = fz;
        if (t > 0) {
            HALF(0, 1, 2, 3);
            HALF(4, 5, 6, 7);
        }

        // ---- head finalize -> dp partials
        float part = 0.f;
#pragma unroll
        for (int r = 0; r < 4; ++r) {
            part += ftanh(h0[r] + b1r[r])     * w2r[r];
            part += ftanh(h1[r] + b1r[4 + r]) * w2r[4 + r];
        }
        part += __shfl_xor(part, 16);
        part += __shfl_xor(part, 32);
        if (q == 0) dp_part[par][col][w] = part;

        if (t + 1 < TSTEPS) npf = *(const float2*)(nptr + (size_t)(t + 1) * NDIM);
        bar_lgkm();

        // ---- post-barrier: dp finalize (all lanes), out col2
        const float* dpp = &dp_part[par][col][0];
        float inner = b2v + ((dpp[0] + dpp[1]) + (dpp[2] + dpp[3]))
                          + ((dpp[4] + dpp[5]) + (dpp[6] + dpp[7]));
        float tdp = ftanh(inner);
        if (s == 0 && w == 0 && lane < 16)
            out[((size_t)(b0 + col) * (TSTEPS + 1) + t) * 3 + 2] = 24.0f * tdp;
        if (t == TSTEPS) break;

        // ---- gates: noise chunks + rank-3 x update + LSTM elementwise
        bf16x8 bn0 = *(const bf16x8*)&actn[par][col][(8 * q) ^ swz];
        bf16x8 bn1 = *(const bf16x8*)&actn[par][col][(32 + 8 * q) ^ swz];
        gacc = MFMA16(__builtin_bit_cast(bf16x8, gw[0]), bn0, gacc);
        gacc = MFMA16(__builtin_bit_cast(bf16x8, gw[1]), bn1, gacc);

        const float g0 = gxy[par][col][0], g1 = gxy[par][col][1];
        float ii = gacc[0] + bI + wx0[0] * g0 + wx1[0] * g1 + wx2[0] * tdp;
        float ff = gacc[1] + bF + wx0[1] * g0 + wx1[1] * g1 + wx2[1] * tdp;
        float gg = gacc[2] + bG + wx0[2] * g0 + wx1[2] * g1 + wx2[2] * tdp;
        float oo = gacc[3] + bO + wx0[3] * g0 + wx1[3] * g1 + wx2[3] * tdp;
        float cn = fsig(ff) * creg + fsig(ii) * ftanh(gg);
        creg = cn;
        float hv = fsig(oo) * ftanh(cn);
        uint16_t hb = f2bf(hv);

        // ---- publish h (dual store: fast sc0 -> L2, slow agent -> MALL)
        uint32_t word = ((uint32_t)(t + 1) << 16) | (uint32_t)hb;
        uint64_t wa = WFa + (((t + 1) & 1) ? 2048u : 0u);
        asm volatile("global_store_dword %0, %1, off sc0" :: "v"(wa), "v"(word) : "memory");
        __hip_atomic_store(&payS[WSw + (((t + 1) & 1) << 9)], word,
                           __ATOMIC_RELAXED, __HIP_MEMORY_SCOPE_AGENT);
    }
}

extern "C" void kernel_launch(void* const* d_in, const int* in_sizes, int n_in,
                              void* d_out, int out_size, void* d_ws, size_t ws_size,
                              hipStream_t stream) {
    (void)in_sizes; (void)n_in; (void)out_size;
    if (ws_size < WSNEED) return;  // fail loudly (output stays poisoned)

    const float* noise = (const float*)d_in[0];
    const float* gap   = (const float*)d_in[1];
    const float* W_ih  = (const float*)d_in[2];
    const float* W_hh  = (const float*)d_in[3];
    const float* b_ih  = (const float*)d_in[4];
    const float* b_hh  = (const float*)d_in[5];
    const float* W1    = (const float*)d_in[6];
    const float* b1    = (const float*)d_in[7];
    const float* W2    = (const float*)d_in[8];
    const float* b2    = (const float*)d_in[9];
    char*  ws  = (char*)d_ws;
    float* out = (float*)d_out;

    hipMemsetAsync(ws + XOFF, 0, IDSB + 2 * PAYB, stream);  // ids + both mailboxes
    hipLaunchKernelGGL(prep_gates, dim3(NGT * NKC), dim3(64), 0, stream, W_ih, W_hh, ws);
    hipLaunchKernelGGL(prep_w1,    dim3(16 * 8),    dim3(64), 0, stream, W1, ws);
    hipLaunchKernelGGL(prep_small, dim3(1), dim3(1024), 0, stream, b_ih, b_hh, ws);
    hipLaunchKernelGGL(lstm_main,  dim3(GROUPS * SLICES), dim3(512), 0, stream,
                       noise, gap, W_ih, b1, W2, b2, ws, out);
}